// Round 2
// baseline (1691.869 us; speedup 1.0000x reference)
//
#include <hip/hip_runtime.h>

#define DD 32

// ---- histogram: cnt[dst[e]] += 1 -------------------------------------------
__global__ void k_hist(const int* __restrict__ dst, int E, int* __restrict__ cnt) {
    int i = blockIdx.x * blockDim.x + threadIdx.x;
    if (i < E) atomicAdd(&cnt[dst[i]], 1);
}

// ---- exclusive scan over cnt[0..n) -> rowptr[0..n], single block ------------
__global__ void k_scan(const int* __restrict__ cnt, int n, int* __restrict__ rowptr) {
    __shared__ int ssum[256];
    int tid = threadIdx.x;
    int chunk = (n + 255) / 256;
    int lo = tid * chunk;
    int hi = lo + chunk; if (hi > n) hi = n;
    int s = 0;
    for (int i = lo; i < hi; ++i) s += cnt[i];
    ssum[tid] = s;
    __syncthreads();
    // Hillis-Steele inclusive scan over 256 partials
    for (int off = 1; off < 256; off <<= 1) {
        int v = (tid >= off) ? ssum[tid - off] : 0;
        __syncthreads();
        ssum[tid] += v;
        __syncthreads();
    }
    int base = (tid == 0) ? 0 : ssum[tid - 1];
    for (int i = lo; i < hi; ++i) { int c = cnt[i]; rowptr[i] = base; base += c; }
    if (tid == 255) rowptr[n] = ssum[255];
}

// ---- fill: csr_src[rowptr[dst]+k] = src ------------------------------------
__global__ void k_fill(const int* __restrict__ src, const int* __restrict__ dst, int E,
                       const int* __restrict__ rowptr, int* __restrict__ fill,
                       int* __restrict__ csr_src) {
    int i = blockIdx.x * blockDim.x + threadIdx.x;
    if (i < E) {
        int v = dst[i];
        int p = rowptr[v] + atomicAdd(&fill[v], 1);
        csr_src[p] = src[i];
    }
}

// ---- fused: out[v] = relu?( xdst[v]@Ws^T + b + mean_{u in N(v)} xsrc[u] @ Wn^T )
// 256 threads = 8 nodes/block, 32 lanes per node (lane d -> feature d).
// Edge indices loaded 32-at-a-time coalesced, broadcast via __shfl so the
// 32 gather addresses per chunk are independent (MLP instead of load chains).
__global__ void k_fused(const float* __restrict__ xsrc, const float* __restrict__ xdst,
                        const int* __restrict__ rowptr, const int* __restrict__ csr_src,
                        const float* __restrict__ Ws, const float* __restrict__ Wn,
                        const float* __restrict__ b,
                        float* __restrict__ out, int n, int do_relu) {
    __shared__ float WsT[DD * DD], WnT[DD * DD], bsh[DD];
    __shared__ float xrow[8][DD], mrow[8][DD];
    int tid = threadIdx.x;
    for (int i = tid; i < DD * DD; i += 256) {
        int r = i >> 5, c = i & 31;
        WsT[c * DD + r] = Ws[i];
        WnT[c * DD + r] = Wn[i];
    }
    if (tid < DD) bsh[tid] = b[tid];
    int g = tid >> 5;       // node slot
    int d = tid & 31;       // feature
    int v = blockIdx.x * 8 + g;
    if (v < n) {
        int rs = rowptr[v], re = rowptr[v + 1];
        float sum = 0.f;
        for (int j0 = rs; j0 < re; j0 += 32) {
            int nj = re - j0; if (nj > 32) nj = 32;
            int myi = (d < nj) ? csr_src[j0 + d] : 0;
            for (int jj = 0; jj < nj; ++jj) {
                int s = __shfl(myi, jj, 32);
                sum += xsrc[(size_t)s * DD + d];
            }
        }
        float degf = (float)(re - rs);
        mrow[g][d] = sum / fmaxf(degf, 1.0f);
        xrow[g][d] = xdst[(size_t)v * DD + d];
    }
    __syncthreads();
    if (v < n) {
        float s2 = bsh[d];
#pragma unroll
        for (int k = 0; k < DD; ++k) {
            s2 += xrow[g][k] * WsT[k * DD + d] + mrow[g][k] * WnT[k * DD + d];
        }
        if (do_relu) s2 = fmaxf(s2, 0.f);
        out[(size_t)v * DD + d] = s2;   // in-place over xdst is safe: row v only
    }
}

extern "C" void kernel_launch(void* const* d_in, const int* in_sizes, int n_in,
                              void* d_out, int out_size, void* d_ws, size_t ws_size,
                              hipStream_t stream) {
    const float* x_user = (const float*)d_in[0];
    const float* x_item = (const float*)d_in[1];
    const int*   ui_src = (const int*)d_in[2];
    const int*   ui_dst = (const int*)d_in[3];
    const int*   iu_src = (const int*)d_in[4];
    const int*   iu_dst = (const int*)d_in[5];
    const float* Ws_ui1 = (const float*)d_in[6];
    const float* Wn_ui1 = (const float*)d_in[7];
    const float* Ws_iu1 = (const float*)d_in[8];
    const float* Wn_iu1 = (const float*)d_in[9];
    const float* Ws_ui2 = (const float*)d_in[10];
    const float* Wn_ui2 = (const float*)d_in[11];
    const float* Ws_iu2 = (const float*)d_in[12];
    const float* Wn_iu2 = (const float*)d_in[13];
    const float* b_ui1  = (const float*)d_in[14];
    const float* b_iu1  = (const float*)d_in[15];
    const float* b_ui2  = (const float*)d_in[16];
    const float* b_iu2  = (const float*)d_in[17];

    int NU = in_sizes[0] / DD;
    int NI = in_sizes[1] / DD;
    int E  = in_sizes[2];
    int NMAX = NU > NI ? NU : NI;

    // ---- workspace layout ----
    // O_item [NI*DD floats] | csr_ui [E ints] | csr_iu [E ints] |
    // rowptr_item [NI+1] | rowptr_user [NU+1] | cnt/fill [NMAX]
    float* O_item      = (float*)d_ws;
    int*   csr_ui      = (int*)(O_item + (size_t)NI * DD);
    int*   csr_iu      = csr_ui + E;
    int*   rowptr_item = csr_iu + E;
    int*   rowptr_user = rowptr_item + (NI + 1);
    int*   cnt         = rowptr_user + (NU + 1);

    // layer-1 hidden states live in d_out: h_user then h_item
    float* h_user = (float*)d_out;
    float* h_item = h_user + (size_t)NU * DD;

    const int tb = 256;
    int egrid = (E + tb - 1) / tb;

    // ---- build CSR for ui relation (dst = item) ----
    hipMemsetAsync(cnt, 0, (size_t)NMAX * sizeof(int), stream);
    hipLaunchKernelGGL(k_hist, dim3(egrid), dim3(tb), 0, stream, ui_dst, E, cnt);
    hipLaunchKernelGGL(k_scan, dim3(1), dim3(256), 0, stream, cnt, NI, rowptr_item);
    hipMemsetAsync(cnt, 0, (size_t)NMAX * sizeof(int), stream);
    hipLaunchKernelGGL(k_fill, dim3(egrid), dim3(tb), 0, stream,
                       ui_src, ui_dst, E, rowptr_item, cnt, csr_ui);

    // ---- build CSR for iu relation (dst = user) ----
    hipMemsetAsync(cnt, 0, (size_t)NMAX * sizeof(int), stream);
    hipLaunchKernelGGL(k_hist, dim3(egrid), dim3(tb), 0, stream, iu_dst, E, cnt);
    hipLaunchKernelGGL(k_scan, dim3(1), dim3(256), 0, stream, cnt, NU, rowptr_user);
    hipMemsetAsync(cnt, 0, (size_t)NMAX * sizeof(int), stream);
    hipLaunchKernelGGL(k_fill, dim3(egrid), dim3(tb), 0, stream,
                       iu_src, iu_dst, E, rowptr_user, cnt, csr_iu);

    // ---- layer 1 (relu): h_item from x_user, h_user from x_item ----
    hipLaunchKernelGGL(k_fused, dim3((NI + 7) / 8), dim3(tb), 0, stream,
                       x_user, x_item, rowptr_item, csr_ui, Ws_ui1, Wn_ui1, b_ui1,
                       h_item, NI, 1);
    hipLaunchKernelGGL(k_fused, dim3((NU + 7) / 8), dim3(tb), 0, stream,
                       x_item, x_user, rowptr_user, csr_iu, Ws_iu1, Wn_iu1, b_iu1,
                       h_user, NU, 1);

    // ---- layer 2 (no relu) ----
    // o_item -> workspace (h_item still needed by o_user's gather)
    hipLaunchKernelGGL(k_fused, dim3((NI + 7) / 8), dim3(tb), 0, stream,
                       h_user, h_item, rowptr_item, csr_ui, Ws_ui2, Wn_ui2, b_ui2,
                       O_item, NI, 0);
    // o_user -> in place over h_user (self row read-before-write within block)
    hipLaunchKernelGGL(k_fused, dim3((NU + 7) / 8), dim3(tb), 0, stream,
                       h_item, h_user, rowptr_user, csr_iu, Ws_iu2, Wn_iu2, b_iu2,
                       h_user, NU, 0);

    // ---- move o_item into d_out ----
    hipMemcpyAsync(h_item, O_item, (size_t)NI * DD * sizeof(float),
                   hipMemcpyDeviceToDevice, stream);
}

// Round 4
// 968.390 us; speedup vs baseline: 1.7471x; 1.7471x over previous
//
#include <hip/hip_runtime.h>

#define DD 32
#define NB 256
#define NT 256

// ---- histogram for both relations in one launch -----------------------------
__global__ void k_hist2(const int* __restrict__ dstA, int EA, int* __restrict__ cntA,
                        const int* __restrict__ dstB, int EB, int* __restrict__ cntB,
                        int blocksPer) {
    int b = blockIdx.x;
    const int* dst; int* cnt; int E; int bb;
    if (b < blocksPer) { dst = dstA; cnt = cntA; E = EA; bb = b; }
    else               { dst = dstB; cnt = cntB; E = EB; bb = b - blocksPer; }
    int i = bb * blockDim.x + threadIdx.x;
    if (i < E) atomicAdd(&cnt[dst[i]], 1);
}

// ---- scan pass 1: per-thread partial sums + per-block sums ------------------
__global__ void k_scan_partial(const int* __restrict__ cntA, int nA,
                               const int* __restrict__ cntB, int nB,
                               int* __restrict__ tsum, int* __restrict__ bsum) {
    __shared__ int red[NT];
    int sel = blockIdx.x / NB;
    int b   = blockIdx.x % NB;
    const int* cnt = sel ? cntB : cntA;
    int n = sel ? nB : nA;
    int sub = (n + NB * NT - 1) / (NB * NT);
    int t = threadIdx.x;
    int gt = b * NT + t;
    long long lo = (long long)gt * sub;
    int s = 0;
    for (int i = 0; i < sub; ++i) {
        long long idx = lo + i;
        if (idx < n) s += cnt[idx];
    }
    tsum[(size_t)sel * NB * NT + gt] = s;
    red[t] = s;
    __syncthreads();
    for (int off = NT / 2; off > 0; off >>= 1) {
        if (t < off) red[t] += red[t + off];
        __syncthreads();
    }
    if (t == 0) bsum[sel * NB + b] = red[0];
}

// ---- scan pass 2: exclusive scan of block sums (both arrays, one block) -----
__global__ void k_scan_bsum(int* __restrict__ bsum) {
    __shared__ int sh[NB];
    int t = threadIdx.x;
    for (int sel = 0; sel < 2; ++sel) {
        int v = bsum[sel * NB + t];
        sh[t] = v;
        __syncthreads();
        for (int off = 1; off < NB; off <<= 1) {
            int u = (t >= off) ? sh[t - off] : 0;
            __syncthreads();
            sh[t] += u;
            __syncthreads();
        }
        bsum[sel * NB + t] = sh[t] - v;
        __syncthreads();
    }
}

// ---- scan pass 3: write rowptr ----------------------------------------------
__global__ void k_scan_write(const int* __restrict__ cntA, int nA, int* __restrict__ rpA,
                             const int* __restrict__ cntB, int nB, int* __restrict__ rpB,
                             const int* __restrict__ tsum, const int* __restrict__ bsum) {
    __shared__ int sh[NT];
    int sel = blockIdx.x / NB;
    int b   = blockIdx.x % NB;
    const int* cnt = sel ? cntB : cntA;
    int* rp = sel ? rpB : rpA;
    int n = sel ? nB : nA;
    int sub = (n + NB * NT - 1) / (NB * NT);
    int t = threadIdx.x;
    int gt = b * NT + t;
    int v = tsum[(size_t)sel * NB * NT + gt];
    sh[t] = v;
    __syncthreads();
    for (int off = 1; off < NT; off <<= 1) {
        int u = (t >= off) ? sh[t - off] : 0;
        __syncthreads();
        sh[t] += u;
        __syncthreads();
    }
    int base = bsum[sel * NB + b] + sh[t] - v;
    long long lo = (long long)gt * sub;
    long long hi = lo + sub; if (hi > n) hi = n;
    for (long long i = lo; i < hi; ++i) { int c = cnt[i]; rp[i] = base; base += c; }
    if (lo < n && hi == n) rp[n] = base;
}

// ---- fill both CSRs in one launch -------------------------------------------
__global__ void k_fill2(const int* __restrict__ srcA, const int* __restrict__ dstA, int EA,
                        const int* __restrict__ rpA, int* __restrict__ fillA, int* __restrict__ csrA,
                        const int* __restrict__ srcB, const int* __restrict__ dstB, int EB,
                        const int* __restrict__ rpB, int* __restrict__ fillB, int* __restrict__ csrB,
                        int blocksPer) {
    int b = blockIdx.x;
    const int *src, *dst, *rp; int *fill, *csr; int E, bb;
    if (b < blocksPer) { src = srcA; dst = dstA; rp = rpA; fill = fillA; csr = csrA; E = EA; bb = b; }
    else               { src = srcB; dst = dstB; rp = rpB; fill = fillB; csr = csrB; E = EB; bb = b - blocksPer; }
    int i = bb * blockDim.x + threadIdx.x;
    if (i < E) {
        int v = dst[i];
        int p = rp[v] + atomicAdd(&fill[v], 1);
        csr[p] = src[i];
    }
}

// ---- fused: out[v] = relu?( xdst[v]@Ws^T + b + mean_{u in N(v)} xsrc[u] @ Wn^T )
__global__ void k_fused(const float* __restrict__ xsrc, const float* __restrict__ xdst,
                        const int* __restrict__ rowptr, const int* __restrict__ csr_src,
                        const float* __restrict__ Ws, const float* __restrict__ Wn,
                        const float* __restrict__ b,
                        float* __restrict__ out, int n, int do_relu) {
    __shared__ float WsT[DD * DD], WnT[DD * DD], bsh[DD];
    __shared__ float xrow[8][DD], mrow[8][DD];
    int tid = threadIdx.x;
    for (int i = tid; i < DD * DD; i += 256) {
        int r = i >> 5, c = i & 31;
        WsT[c * DD + r] = Ws[i];
        WnT[c * DD + r] = Wn[i];
    }
    if (tid < DD) bsh[tid] = b[tid];
    int g = tid >> 5;
    int d = tid & 31;
    int v = blockIdx.x * 8 + g;
    if (v < n) {
        int rs = rowptr[v], re = rowptr[v + 1];
        int el = d >> 3;   // edge slot 0..3
        int q  = d & 7;    // float4 quarter 0..7
        float ax = 0.f, ay = 0.f, az = 0.f, aw = 0.f;
        for (int j0 = rs; j0 < re; j0 += 32) {
            int nj = re - j0; if (nj > 32) nj = 32;
            int myi = (d < nj) ? csr_src[j0 + d] : 0;
            for (int c0 = 0; c0 < nj; c0 += 4) {
                int jj = c0 + el;
                int s = __shfl(myi, jj, 32);
                if (jj < nj) {
                    const float4* row = (const float4*)(xsrc + (size_t)s * DD);
                    float4 x4 = row[q];
                    ax += x4.x; ay += x4.y; az += x4.z; aw += x4.w;
                }
            }
        }
        ax += __shfl_xor(ax, 8, 32);  ay += __shfl_xor(ay, 8, 32);
        az += __shfl_xor(az, 8, 32);  aw += __shfl_xor(aw, 8, 32);
        ax += __shfl_xor(ax, 16, 32); ay += __shfl_xor(ay, 16, 32);
        az += __shfl_xor(az, 16, 32); aw += __shfl_xor(aw, 16, 32);
        float degf = (float)(re - rs);
        float rinv = 1.0f / fmaxf(degf, 1.0f);
        if (el == 0) {
            float4 m4; m4.x = ax * rinv; m4.y = ay * rinv; m4.z = az * rinv; m4.w = aw * rinv;
            ((float4*)(&mrow[g][0]))[q] = m4;
        }
        xrow[g][d] = xdst[(size_t)v * DD + d];
    }
    __syncthreads();
    if (v < n) {
        float s2 = bsh[d];
#pragma unroll
        for (int k = 0; k < DD; ++k) {
            s2 += xrow[g][k] * WsT[k * DD + d] + mrow[g][k] * WnT[k * DD + d];
        }
        if (do_relu) s2 = fmaxf(s2, 0.f);
        out[(size_t)v * DD + d] = s2;
    }
}

extern "C" void kernel_launch(void* const* d_in, const int* in_sizes, int n_in,
                              void* d_out, int out_size, void* d_ws, size_t ws_size,
                              hipStream_t stream) {
    const float* x_user = (const float*)d_in[0];
    const float* x_item = (const float*)d_in[1];
    const int*   ui_src = (const int*)d_in[2];
    const int*   ui_dst = (const int*)d_in[3];
    const int*   iu_src = (const int*)d_in[4];
    const int*   iu_dst = (const int*)d_in[5];
    const float* Ws_ui1 = (const float*)d_in[6];
    const float* Wn_ui1 = (const float*)d_in[7];
    const float* Ws_iu1 = (const float*)d_in[8];
    const float* Wn_iu1 = (const float*)d_in[9];
    const float* Ws_ui2 = (const float*)d_in[10];
    const float* Wn_ui2 = (const float*)d_in[11];
    const float* Ws_iu2 = (const float*)d_in[12];
    const float* Wn_iu2 = (const float*)d_in[13];
    const float* b_ui1  = (const float*)d_in[14];
    const float* b_iu1  = (const float*)d_in[15];
    const float* b_ui2  = (const float*)d_in[16];
    const float* b_iu2  = (const float*)d_in[17];

    int NU = in_sizes[0] / DD;
    int NI = in_sizes[1] / DD;
    int E  = in_sizes[2];
    int NMAX = (NU > NI) ? NU : NI;

    // workspace layout
    char* wp = (char*)d_ws;
    float* O_item = (float*)wp;               wp += (size_t)NI * DD * sizeof(float);
    int* csr_ui   = (int*)wp;                 wp += (size_t)E * sizeof(int);
    int* csr_iu   = (int*)wp;                 wp += (size_t)E * sizeof(int);
    int* rp_item  = (int*)wp;                 wp += (size_t)(NI + 1) * sizeof(int);
    int* rp_user  = (int*)wp;                 wp += (size_t)(NU + 1) * sizeof(int);
    int* cntI     = (int*)wp;                 wp += (size_t)NMAX * sizeof(int);
    int* cntU     = (int*)wp;                 wp += (size_t)NMAX * sizeof(int);
    int* fillI    = (int*)wp;                 wp += (size_t)NMAX * sizeof(int);
    int* fillU    = (int*)wp;                 wp += (size_t)NMAX * sizeof(int);
    int* tsum     = (int*)wp;                 wp += (size_t)2 * NB * NT * sizeof(int);
    int* bsum     = (int*)wp;

    float* h_user = (float*)d_out;
    float* h_item = h_user + (size_t)NU * DD;

    const int tb = 256;
    int egrid = (E + tb - 1) / tb;

    // ---- CSR build ----
    (void)hipMemsetAsync(cntI, 0, (size_t)4 * NMAX * sizeof(int), stream);
    hipLaunchKernelGGL(k_hist2, dim3(2 * egrid), dim3(tb), 0, stream,
                       ui_dst, E, cntI, iu_dst, E, cntU, egrid);
    hipLaunchKernelGGL(k_scan_partial, dim3(2 * NB), dim3(NT), 0, stream,
                       cntI, NI, cntU, NU, tsum, bsum);
    hipLaunchKernelGGL(k_scan_bsum, dim3(1), dim3(NB), 0, stream, bsum);
    hipLaunchKernelGGL(k_scan_write, dim3(2 * NB), dim3(NT), 0, stream,
                       cntI, NI, rp_item, cntU, NU, rp_user, tsum, bsum);
    hipLaunchKernelGGL(k_fill2, dim3(2 * egrid), dim3(tb), 0, stream,
                       ui_src, ui_dst, E, rp_item, fillI, csr_ui,
                       iu_src, iu_dst, E, rp_user, fillU, csr_iu, egrid);

    // ---- layer 1 (relu) ----
    hipLaunchKernelGGL(k_fused, dim3((NI + 7) / 8), dim3(tb), 0, stream,
                       x_user, x_item, rp_item, csr_ui, Ws_ui1, Wn_ui1, b_ui1,
                       h_item, NI, 1);
    hipLaunchKernelGGL(k_fused, dim3((NU + 7) / 8), dim3(tb), 0, stream,
                       x_item, x_user, rp_user, csr_iu, Ws_iu1, Wn_iu1, b_iu1,
                       h_user, NU, 1);

    // ---- layer 2 (no relu) ----
    hipLaunchKernelGGL(k_fused, dim3((NI + 7) / 8), dim3(tb), 0, stream,
                       h_user, h_item, rp_item, csr_ui, Ws_ui2, Wn_ui2, b_ui2,
                       O_item, NI, 0);
    hipLaunchKernelGGL(k_fused, dim3((NU + 7) / 8), dim3(tb), 0, stream,
                       h_item, h_user, rp_user, csr_iu, Ws_iu2, Wn_iu2, b_iu2,
                       h_user, NU, 0);

    (void)hipMemcpyAsync(h_item, O_item, (size_t)NI * DD * sizeof(float),
                         hipMemcpyDeviceToDevice, stream);
}